// Round 4
// baseline (128.263 us; speedup 1.0000x reference)
//
#include <hip/hip_runtime.h>

// LIF net on MI355X.  Pipeline:
//  1. convert_W: Bt[kt][n][kk^swz] bf16 (relu, K-pad to 832) + wrelu f32
//  2. gemm_hidden: bf16 MFMA, M padded to 65536 (512/b), counted-vmcnt raw-
//     barrier pipeline, transposed epilogue -> Ih[b][h][512] bf16
//  3. scan_h: wave-per-row parallel LIF scan (shfl_up affine composition)
//  4. out_fused: per-b VALU dot (K=256,N=10) -> LDS -> segmented v_o scan
// ws: wrelu @0 (10KB) | Bt @16KB (416KB) | Ih @512KB (33.55MB)

typedef __attribute__((ext_vector_type(4))) float  floatx4;
typedef __attribute__((ext_vector_type(8))) short  shortx8;
typedef unsigned short u16;
typedef unsigned int   u32;

#define B_   128
#define NIN  784
#define NH   256
#define NO   10
#define T_   500
#define KT   13            // ceil(784/64), zero-padded

__device__ __forceinline__ u16 f2bf(float f) {
    union { float f; u32 u; } x; x.f = f;
    u32 r = x.u + 0x7FFFu + ((x.u >> 16) & 1u);   // RNE
    return (u16)(r >> 16);
}
__device__ __forceinline__ float bf2f(u16 u) {
    union { u32 u; float f; } x; x.u = ((u32)u) << 16; return x.f;
}
__device__ __forceinline__ float sigmoid5(float v) {
    return 1.0f / (1.0f + __expf(-5.0f * (v - 1.0f)));
}
__device__ __forceinline__ int swz8(int r) { return (r & 7) ^ ((r >> 3) & 7); }

__device__ __forceinline__ void gload16(const u16* g, u16* l) {
    __builtin_amdgcn_global_load_lds(
        (const __attribute__((address_space(1))) unsigned int*)(const void*)g,
        (__attribute__((address_space(3))) unsigned int*)(void*)l, 16, 0, 0);
}

#define SBAR  __builtin_amdgcn_sched_barrier(0)
#define HBAR  __builtin_amdgcn_s_barrier()

// ---------- Pre-pass: Bt (swizzled bf16 B) + wrelu ----------
__global__ void convert_W(const float* __restrict__ w_ih,
                          const float* __restrict__ w_ho,
                          u16* __restrict__ Bt, float* __restrict__ wrelu) {
    if (blockIdx.x == KT * 64) {        // last block: w_ho relu
        for (int i = threadIdx.x; i < NH * NO; i += 256)
            wrelu[i] = fmaxf(0.f, w_ho[i]);
        return;
    }
    const int k = blockIdx.x;           // 0..831
    const int n = threadIdx.x;          // 0..255
    float f = (k < NIN) ? fmaxf(0.f, w_ih[k * NH + n]) : 0.f;
    const int kt = k >> 6, kk = k & 63;
    Bt[(size_t)kt * (NH * 64) + n * 64 + (kk ^ (swz8(n) << 3))] = f2bf(f);
}

// ---------- Phase A: hidden GEMM (counted-vmcnt pipeline) ----------
// Tile 64m x 256n, BK=64, 512 thr (8 waves 2x4), wave tile 32x64 (2x4 frags).
// M' = 128*512: m = b*512 + t (t>=500 dead, A zeros).  A: thread=(m8,k),
// 2x float4 along t (64B-aligned), transpose+cvt in regs, ds_write_b16
// swizzled.  B: global_load_lds from pre-swizzled Bt.  Raw s_barrier +
// counted s_waitcnt: A prefetch (2 ahead) never drained.
__global__ __launch_bounds__(512, 4) void gemm_hidden(
    const float* __restrict__ spikes,   // [128][784][500] f32
    const u16* __restrict__ Bt,
    u16* __restrict__ Ih)               // [128][256][512] bf16
{
    __shared__ u16 As[2][64 * 64];      // 8KB x2
    __shared__ u16 Bs[2][256 * 64];     // 32KB x2

    const int tid  = threadIdx.x;
    const int row0 = blockIdx.x * 64;   // 1024 blocks
    const int bb   = row0 >> 9;
    const int t0   = row0 & 511;

    // A staging: thread covers m = m8..m8+7 (t = tt..tt+7) at k = kA
    const int m8 = (tid & 7) * 8;
    const int kA = tid >> 3;            // 0..63
    const int tt = t0 + m8;
    const bool tok = (tt < T_);
    const float* abase = spikes + (size_t)bb * (NIN * T_) + tt;

    const int lane = tid & 63, wid = tid >> 6;
    const int wm = wid >> 2, wn = wid & 3;
    const int lg = lane >> 4, lr = lane & 15;
    int aOff[2], bOff[4];
#pragma unroll
    for (int i = 0; i < 2; ++i) {
        const int m = wm * 32 + i * 16 + lr;
        aOff[i] = m * 64 + ((lg * 8) ^ (swz8(m) << 3));
    }
#pragma unroll
    for (int i = 0; i < 4; ++i) {
        const int n = wn * 64 + i * 16 + lr;
        bOff[i] = n * 64 + ((lg * 8) ^ (swz8(n) << 3));
    }

    floatx4 acc[2][4];
#pragma unroll
    for (int i = 0; i < 2; ++i)
#pragma unroll
        for (int j = 0; j < 4; ++j) acc[i][j] = (floatx4)0.f;

    // always-issue loads (uniform vmcnt bookkeeping): clamp addr, select zero
#define LOADA(va, itv) {                                                       \
        const int kb = (itv) * 64 + kA;                                        \
        const bool ok = (kb < NIN) && tok;                                     \
        const float* p = ok ? (abase + (size_t)kb * T_) : spikes;              \
        floatx4 v0 = *(const floatx4*)p;                                       \
        floatx4 v1 = *(const floatx4*)(p + 4);                                 \
        va[0] = ok ? v0 : (floatx4)0.f;                                        \
        va[1] = ok ? v1 : (floatx4)0.f; }

#define WRITEA(buf, va) { _Pragma("unroll") for (int x = 0; x < 2; ++x)        \
        _Pragma("unroll") for (int q = 0; q < 4; ++q) {                        \
            const int j = 4 * x + q;                                           \
            As[buf][(m8 + j) * 64 + (kA ^ ((j ^ (tid & 7)) << 3))] =           \
                f2bf(va[x][q]); } }

#define STAGEB(buf, itv) { const u16* src = Bt + (size_t)(itv) * (NH * 64);    \
        _Pragma("unroll") for (int c = 0; c < 4; ++c) {                        \
            const int o = c * 4096 + tid * 8;                                  \
            gload16(src + o, &Bs[buf][o]); } }

#define MFMAIT(buf) { _Pragma("unroll") for (int ks = 0; ks < 2; ++ks) {       \
        shortx8 af[2], bfv[4];                                                 \
        _Pragma("unroll") for (int i = 0; i < 2; ++i)                          \
            af[i] = *(const shortx8*)&As[buf][aOff[i] ^ (ks * 32)];            \
        _Pragma("unroll") for (int i = 0; i < 4; ++i)                          \
            bfv[i] = *(const shortx8*)&Bs[buf][bOff[i] ^ (ks * 32)];           \
        _Pragma("unroll") for (int mi = 0; mi < 2; ++mi)                       \
        _Pragma("unroll") for (int ni = 0; ni < 4; ++ni)                       \
            acc[mi][ni] = __builtin_amdgcn_mfma_f32_16x16x32_bf16(             \
                af[mi], bfv[ni], acc[mi][ni], 0, 0, 0); } }

    floatx4 vaP[2], vaQ[2];

    // prologue: order [A0(2), B0(4), A1(2)]
    LOADA(vaP, 0); SBAR;
    STAGEB(0, 0);  SBAR;
    LOADA(vaQ, 1); SBAR;
    asm volatile("s_waitcnt vmcnt(6)" ::: "memory");        // A0 done
    WRITEA(0, vaP);
    asm volatile("s_waitcnt vmcnt(2) lgkmcnt(0)" ::: "memory"); // B0 done
    SBAR; HBAR; SBAR;

    // body: entry outstanding [A(it+1) x2]
#define BODY(it, cur, nxt, vaW, vaL)                                            \
    STAGEB(nxt, (it) + 1); SBAR;                                                \
    LOADA(vaL, (it) + 2);  SBAR;                                                \
    MFMAIT(cur);                                                                \
    asm volatile("s_waitcnt vmcnt(6)" ::: "memory");                            \
    WRITEA(nxt, vaW);                                                           \
    asm volatile("s_waitcnt vmcnt(2) lgkmcnt(0)" ::: "memory");                 \
    SBAR; HBAR; SBAR;

    BODY(0, 0, 1, vaQ, vaP)  BODY(1, 1, 0, vaP, vaQ)
    BODY(2, 0, 1, vaQ, vaP)  BODY(3, 1, 0, vaP, vaQ)
    BODY(4, 0, 1, vaQ, vaP)  BODY(5, 1, 0, vaP, vaQ)
    BODY(6, 0, 1, vaQ, vaP)  BODY(7, 1, 0, vaP, vaQ)
    BODY(8, 0, 1, vaQ, vaP)  BODY(9, 1, 0, vaP, vaQ)
    BODY(10, 0, 1, vaQ, vaP)

    // tail it=11: entry [A12 x2]
    STAGEB(0, 12); SBAR;
    MFMAIT(1);
    asm volatile("s_waitcnt vmcnt(4)" ::: "memory");        // A12 done
    WRITEA(0, vaP);
    asm volatile("s_waitcnt vmcnt(0) lgkmcnt(0)" ::: "memory");
    SBAR; HBAR; SBAR;
    MFMAIT(0);                                              // tile 12
    asm volatile("s_waitcnt lgkmcnt(0)" ::: "memory");
    SBAR; HBAR; SBAR;

    // epilogue: transpose via LDS (reuse Bs[0]) -> Ih[b][n][t0+ m]
    u16* Cs = &Bs[0][0];                                    // [256][64] u16
#pragma unroll
    for (int mi = 0; mi < 2; ++mi)
#pragma unroll
        for (int r = 0; r < 4; ++r) {
            const int m = wm * 32 + mi * 16 + lg * 4 + r;
#pragma unroll
            for (int ni = 0; ni < 4; ++ni) {
                const int n = wn * 64 + ni * 16 + lr;
                Cs[n * 64 + (m ^ ((n & 7) << 3))] = f2bf(acc[mi][ni][r]);
            }
        }
    asm volatile("s_waitcnt lgkmcnt(0)" ::: "memory");
    SBAR; HBAR; SBAR;
    {
        const int n  = tid >> 1, mh = tid & 1;
        u16* gdst = Ih + ((size_t)bb * 256 + n) * 512 + t0 + mh * 32;
#pragma unroll
        for (int j = 0; j < 4; ++j) {
            const uint4 v = *(const uint4*)&Cs[n * 64 + ((mh * 32 + 8 * j) ^ ((n & 7) << 3))];
            *(uint4*)(gdst + 8 * j) = v;
        }
    }
#undef LOADA
#undef WRITEA
#undef STAGEB
#undef MFMAIT
#undef BODY
}

// ---------- Phase B: parallel hidden LIF scan (in place) ----------
// 32768 rows [b][h][512]; one wave per row; lane holds 8 t; affine
// composition scan across lanes (v' = a*v + b, a=0.9^8).
__global__ __launch_bounds__(512) void scan_h(u16* __restrict__ Ih) {
    const int lane = threadIdx.x & 63;
    const int row  = blockIdx.x * 8 + (threadIdx.x >> 6);
    u16* p = Ih + (size_t)row * 512 + lane * 8;
    shortx8 xv = *(const shortx8*)p;
    float I[8];
#pragma unroll
    for (int j = 0; j < 8; ++j) I[j] = bf2f((u16)xv[j]);
    float z = 0.f;
#pragma unroll
    for (int j = 0; j < 8; ++j) z += (I[j] - z) * 0.1f;
    float A = 0.43046721f, Bv = z;                 // 0.9^8
#pragma unroll
    for (int d = 1; d < 64; d <<= 1) {
        const float Au = __shfl_up(A, d);
        const float Bu = __shfl_up(Bv, d);
        if (lane >= d) { Bv = fmaf(A, Bu, Bv); A *= Au; }
    }
    float v = __shfl_up(Bv, 1);
    if (lane == 0) v = 0.f;
#pragma unroll
    for (int j = 0; j < 8; ++j) {
        v += (I[j] - v) * 0.1f;
        xv[j] = (short)f2bf(sigmoid5(v));
    }
    *(shortx8*)p = xv;
}

// ---------- Phase C+D: output dot + segmented v_o scan ----------
// Block per b (512 thr).  Phase1: lane t = tid, acc[10] over h=0..255
// (s reads 128B-coalesced, w from SGPR-friendly uniform loads).
// Phase2: LDS Io[500][10].  Phase3: 25-segment parallel scan -> outputs.
__global__ __launch_bounds__(512) void out_fused(
    const u16* __restrict__ s,          // [128][256][512] bf16
    const float* __restrict__ wr,       // [256][10] relu'd f32
    float* __restrict__ out)
{
    __shared__ float Io[T_ * NO];       // 20KB
    __shared__ float vend[25][NO], vstart[25][NO], psum[25][NO];
    const int b = blockIdx.x, tid = threadIdx.x;

    float acc[NO];
#pragma unroll
    for (int o = 0; o < NO; ++o) acc[o] = 0.f;
    const u16* sb = s + (size_t)b * NH * 512 + tid;
#pragma unroll 2
    for (int h = 0; h < NH; ++h) {
        const float sv = bf2f(sb[h * 512]);
#pragma unroll
        for (int o = 0; o < NO; ++o) acc[o] = fmaf(sv, wr[h * NO + o], acc[o]);
    }
    if (tid < T_) {
#pragma unroll
        for (int o = 0; o < NO; ++o) Io[tid * NO + o] = acc[o];
    }
    __syncthreads();

    const int seg = tid / NO, o = tid - seg * NO;
    if (tid < 250) {
        float v = 0.f;
#pragma unroll
        for (int j = 0; j < 20; ++j)
            v += (Io[(seg * 20 + j) * NO + o] - v) * 0.1f;
        vend[seg][o] = v;
    }
    __syncthreads();
    if (tid < NO) {
        float vs = 0.f;
#pragma unroll
        for (int sg = 0; sg < 25; ++sg) {
            vstart[sg][tid] = vs;
            vs = vend[sg][tid] + 0.12157665459f * vs;   // 0.9^20
        }
    }
    __syncthreads();
    if (tid < 250) {
        float v = vstart[seg][o], ps = 0.f;
#pragma unroll
        for (int j = 0; j < 20; ++j) {
            const int t = seg * 20 + j;
            v += (Io[t * NO + o] - v) * 0.1f;
            const float sv = sigmoid5(v);
            out[(size_t)b * (NO * T_) + (size_t)o * T_ + t] = sv;
            ps += sv;
        }
        psum[seg][o] = ps;
    }
    __syncthreads();
    if (tid < NO) {
        float tot = 0.f;
#pragma unroll
        for (int sg = 0; sg < 25; ++sg) tot += psum[sg][tid];
        out[(size_t)(B_ * NO) * T_ + b * NO + tid] = tot * (1.0f / T_);
    }
}

extern "C" void kernel_launch(void* const* d_in, const int* in_sizes, int n_in,
                              void* d_out, int out_size, void* d_ws, size_t ws_size,
                              hipStream_t stream) {
    (void)in_sizes; (void)n_in; (void)out_size; (void)ws_size;
    const float* spikes = (const float*)d_in[0];   // [128][784][500]
    const float* w_ih   = (const float*)d_in[1];   // [784][256]
    const float* w_ho   = (const float*)d_in[2];   // [256][10]
    float* out = (float*)d_out;

    float* wrelu = (float*)d_ws;                            // 10KB @0
    u16*   Bt    = (u16*)((char*)d_ws + 16384);             // 416KB
    u16*   Ih    = (u16*)((char*)d_ws + 524288);            // 33.55MB

    convert_W  <<<KT * 64 + 1, 256, 0, stream>>>(w_ih, w_ho, Bt, wrelu);
    gemm_hidden<<<1024, 512, 0, stream>>>(spikes, Bt, Ih);
    scan_h     <<<4096, 512, 0, stream>>>(Ih);
    out_fused  <<<B_, 512, 0, stream>>>(Ih, wrelu, out);
}